// Round 1
// baseline (1216.817 us; speedup 1.0000x reference)
//
#include <hip/hip_runtime.h>
#include <hip/hip_bf16.h>
#include <cstdint>

#define DM   1024
#define SEQ  2048
#define NB   4
#define NH   16
#define LOG2E 1.4426950408889634f

typedef __bf16 bf16x8 __attribute__((ext_vector_type(8)));
typedef float  f32x4  __attribute__((ext_vector_type(4)));
typedef unsigned short u16;
typedef u16 u16x4 __attribute__((ext_vector_type(4)));
typedef u16 u16x8 __attribute__((ext_vector_type(8)));

__device__ __forceinline__ u16 f2bf(float f) {
    uint32_t u = __builtin_bit_cast(uint32_t, f);
    u = (u + 0x7FFFu + ((u >> 16) & 1u)) >> 16;
    return (u16)u;
}
__device__ __forceinline__ float ex2(float x) { return __builtin_amdgcn_exp2f(x); }
__device__ __forceinline__ bf16x8 ld_bf8(const u16* p) {
    return __builtin_bit_cast(bf16x8, *reinterpret_cast<const u16x8*>(p));
}

// ---------------- projection GEMM: fp32 A [8192,1024] x fp32 W [1024,1024] -> bf16 out
// blockIdx.z selects which of Q/K/V
__global__ __launch_bounds__(256) void proj_gemm(
    const float* __restrict__ A0, const float* __restrict__ A1, const float* __restrict__ A2,
    const float* __restrict__ W0, const float* __restrict__ W1, const float* __restrict__ W2,
    u16* __restrict__ O0, u16* __restrict__ O1, u16* __restrict__ O2)
{
    const float* A; const float* W; u16* Out;
    if (blockIdx.z == 0) { A = A0; W = W0; Out = O0; }
    else if (blockIdx.z == 1) { A = A1; W = W1; Out = O1; }
    else { A = A2; W = W2; Out = O2; }

    __shared__ u16 As[128][40];
    __shared__ u16 Bs[128][40];
    const int t = threadIdx.x;
    const int m0 = blockIdx.x * 128;
    const int n0 = blockIdx.y * 128;
    const int w = t >> 6, l = t & 63;
    const int wr = (w >> 1) * 64, wc = (w & 1) * 64;
    const int lr = l & 15, lk = l >> 4;

    f32x4 acc[4][4] = {};
    for (int kt = 0; kt < DM; kt += 32) {
        #pragma unroll
        for (int ii = 0; ii < 4; ++ii) {
            int fidx = t + ii * 256;
            int row = fidx >> 3, c4 = fidx & 7;
            const float4 v = *reinterpret_cast<const float4*>(A + (size_t)(m0 + row) * DM + kt + c4 * 4);
            u16x4 o; o[0] = f2bf(v.x); o[1] = f2bf(v.y); o[2] = f2bf(v.z); o[3] = f2bf(v.w);
            *reinterpret_cast<u16x4*>(&As[row][c4 * 4]) = o;
        }
        #pragma unroll
        for (int ii = 0; ii < 4; ++ii) {
            int fidx = t + ii * 256;
            int kk = fidx >> 5, c4 = fidx & 31;
            const float4 v = *reinterpret_cast<const float4*>(W + (size_t)(kt + kk) * DM + n0 + c4 * 4);
            Bs[c4 * 4 + 0][kk] = f2bf(v.x);
            Bs[c4 * 4 + 1][kk] = f2bf(v.y);
            Bs[c4 * 4 + 2][kk] = f2bf(v.z);
            Bs[c4 * 4 + 3][kk] = f2bf(v.w);
        }
        __syncthreads();
        bf16x8 af[4], bfr[4];
        #pragma unroll
        for (int mi = 0; mi < 4; ++mi) af[mi] = ld_bf8(&As[wr + mi * 16 + lr][lk * 8]);
        #pragma unroll
        for (int ni = 0; ni < 4; ++ni) bfr[ni] = ld_bf8(&Bs[wc + ni * 16 + lr][lk * 8]);
        #pragma unroll
        for (int mi = 0; mi < 4; ++mi)
            #pragma unroll
            for (int ni = 0; ni < 4; ++ni)
                acc[mi][ni] = __builtin_amdgcn_mfma_f32_16x16x32_bf16(af[mi], bfr[ni], acc[mi][ni], 0, 0, 0);
        __syncthreads();
    }
    #pragma unroll
    for (int mi = 0; mi < 4; ++mi)
        #pragma unroll
        for (int ni = 0; ni < 4; ++ni)
            #pragma unroll
            for (int i = 0; i < 4; ++i) {
                int r = m0 + wr + mi * 16 + lk * 4 + i;
                int c = n0 + wc + ni * 16 + lr;
                Out[(size_t)r * DM + c] = f2bf(acc[mi][ni][i]);
            }
}

// ---------------- output GEMM: bf16 ctx [8192,1024] x fp32 W_fc -> fp32 out + residual
__global__ __launch_bounds__(256) void out_gemm(
    const u16* __restrict__ A, const float* __restrict__ W,
    const float* __restrict__ resid, float* __restrict__ Out)
{
    __shared__ u16 As[128][40];
    __shared__ u16 Bs[128][40];
    const int t = threadIdx.x;
    const int m0 = blockIdx.x * 128;
    const int n0 = blockIdx.y * 128;
    const int w = t >> 6, l = t & 63;
    const int wr = (w >> 1) * 64, wc = (w & 1) * 64;
    const int lr = l & 15, lk = l >> 4;

    f32x4 acc[4][4] = {};
    for (int kt = 0; kt < DM; kt += 32) {
        #pragma unroll
        for (int ii = 0; ii < 2; ++ii) {
            int fidx = t + ii * 256;
            int row = fidx >> 2, c8 = fidx & 3;
            u16x8 v = *reinterpret_cast<const u16x8*>(A + (size_t)(m0 + row) * DM + kt + c8 * 8);
            *reinterpret_cast<u16x8*>(&As[row][c8 * 8]) = v;
        }
        #pragma unroll
        for (int ii = 0; ii < 4; ++ii) {
            int fidx = t + ii * 256;
            int kk = fidx >> 5, c4 = fidx & 31;
            const float4 v = *reinterpret_cast<const float4*>(W + (size_t)(kt + kk) * DM + n0 + c4 * 4);
            Bs[c4 * 4 + 0][kk] = f2bf(v.x);
            Bs[c4 * 4 + 1][kk] = f2bf(v.y);
            Bs[c4 * 4 + 2][kk] = f2bf(v.z);
            Bs[c4 * 4 + 3][kk] = f2bf(v.w);
        }
        __syncthreads();
        bf16x8 af[4], bfr[4];
        #pragma unroll
        for (int mi = 0; mi < 4; ++mi) af[mi] = ld_bf8(&As[wr + mi * 16 + lr][lk * 8]);
        #pragma unroll
        for (int ni = 0; ni < 4; ++ni) bfr[ni] = ld_bf8(&Bs[wc + ni * 16 + lr][lk * 8]);
        #pragma unroll
        for (int mi = 0; mi < 4; ++mi)
            #pragma unroll
            for (int ni = 0; ni < 4; ++ni)
                acc[mi][ni] = __builtin_amdgcn_mfma_f32_16x16x32_bf16(af[mi], bfr[ni], acc[mi][ni], 0, 0, 0);
        __syncthreads();
    }
    #pragma unroll
    for (int mi = 0; mi < 4; ++mi)
        #pragma unroll
        for (int ni = 0; ni < 4; ++ni)
            #pragma unroll
            for (int i = 0; i < 4; ++i) {
                int r = m0 + wr + mi * 16 + lk * 4 + i;
                int c = n0 + wc + ni * 16 + lr;
                Out[(size_t)r * DM + c] = acc[mi][ni][i] + resid[(size_t)r * DM + c];
            }
}

// ---------------- V transpose: Vb[b*2048+s][h*64+dv] -> Vt[((b*16+h)*64+dv)][s]
__global__ __launch_bounds__(256) void v_transpose(const u16* __restrict__ Vb, u16* __restrict__ Vt)
{
    __shared__ u16 T[64][72];
    const int t = threadIdx.x;
    const int s0 = blockIdx.x * 64;
    const int h = blockIdx.y, b = blockIdx.z;
    #pragma unroll
    for (int ii = 0; ii < 4; ++ii) {
        int fidx = t + ii * 256;
        int row = fidx >> 4, c4 = fidx & 15;
        u16x4 v = *reinterpret_cast<const u16x4*>(Vb + (size_t)(b * SEQ + s0 + row) * DM + h * 64 + c4 * 4);
        T[c4 * 4 + 0][row] = v[0];
        T[c4 * 4 + 1][row] = v[1];
        T[c4 * 4 + 2][row] = v[2];
        T[c4 * 4 + 3][row] = v[3];
    }
    __syncthreads();
    #pragma unroll
    for (int ii = 0; ii < 4; ++ii) {
        int fidx = t + ii * 256;
        int dv = fidx >> 4, s4 = fidx & 15;
        u16x4 v;
        v[0] = T[dv][s4 * 4 + 0]; v[1] = T[dv][s4 * 4 + 1];
        v[2] = T[dv][s4 * 4 + 2]; v[3] = T[dv][s4 * 4 + 3];
        *reinterpret_cast<u16x4*>(Vt + ((size_t)((b * NH + h) * 64 + dv)) * SEQ + s0 + s4 * 4) = v;
    }
}

// ---------------- attention: per block (qt, h, b), 4 waves x 16 q-rows, two-pass flash
__global__ __launch_bounds__(256) void attn_kernel(
    const u16* __restrict__ Qb, const u16* __restrict__ Kb, const u16* __restrict__ Vt,
    const unsigned char* __restrict__ mask,
    float* __restrict__ attn_out, u16* __restrict__ ctx)
{
    __shared__ u16 P[4][16][40];
    const int t = threadIdx.x;
    const int w = t >> 6, l = t & 63;
    const int lr = l & 15, lk = l >> 4;
    const int qt = blockIdx.x, h = blockIdx.y, b = blockIdx.z;
    const int q0 = qt * 64 + w * 16;

    const size_t rowQ = (size_t)(b * SEQ + q0 + lr) * DM + h * 64 + lk * 8;
    const bf16x8 aq0 = ld_bf8(Qb + rowQ);
    const bf16x8 aq1 = ld_bf8(Qb + rowQ + 32);
    const size_t maskBase = (size_t)b * SEQ * SEQ;

    float m[4], lsum[4];
    #pragma unroll
    for (int i = 0; i < 4; ++i) { m[i] = -1e30f; lsum[i] = 0.f; }

    // pass 1: online max + sum
    for (int kt = 0; kt < SEQ / 16; ++kt) {
        size_t rowK = (size_t)(b * SEQ + kt * 16 + lr) * DM + h * 64 + lk * 8;
        bf16x8 bk0 = ld_bf8(Kb + rowK);
        bf16x8 bk1 = ld_bf8(Kb + rowK + 32);
        f32x4 s4 = {};
        s4 = __builtin_amdgcn_mfma_f32_16x16x32_bf16(aq0, bk0, s4, 0, 0, 0);
        s4 = __builtin_amdgcn_mfma_f32_16x16x32_bf16(aq1, bk1, s4, 0, 0, 0);
        int col = kt * 16 + lr;
        #pragma unroll
        for (int i = 0; i < 4; ++i) {
            int q = q0 + lk * 4 + i;
            float s = s4[i] * 0.125f;
            if (mask[maskBase + (size_t)q * SEQ + col]) s = -1e9f;
            float mn = fmaxf(m[i], s);
            lsum[i] = lsum[i] * ex2((m[i] - mn) * LOG2E) + ex2((s - mn) * LOG2E);
            m[i] = mn;
        }
    }
    // combine across the 16 lanes holding each row
    #pragma unroll
    for (int i = 0; i < 4; ++i) {
        #pragma unroll
        for (int off = 1; off < 16; off <<= 1) {
            float mo = __shfl_xor(m[i], off);
            float lo = __shfl_xor(lsum[i], off);
            float mn = fmaxf(m[i], mo);
            lsum[i] = lsum[i] * ex2((m[i] - mn) * LOG2E) + lo * ex2((mo - mn) * LOG2E);
            m[i] = mn;
        }
    }
    float invl[4];
    #pragma unroll
    for (int i = 0; i < 4; ++i) invl[i] = 1.0f / lsum[i];

    // pass 2: recompute scores, write normalized attn, accumulate PV
    f32x4 cacc[4] = {};
    const size_t attnBase = (size_t)(b * NH + h) * SEQ * SEQ;
    const size_t vtBase = (size_t)((b * NH + h) * 64) * SEQ;
    for (int kt2 = 0; kt2 < SEQ / 32; ++kt2) {
        #pragma unroll
        for (int sub = 0; sub < 2; ++sub) {
            int kt = kt2 * 2 + sub;
            size_t rowK = (size_t)(b * SEQ + kt * 16 + lr) * DM + h * 64 + lk * 8;
            bf16x8 bk0 = ld_bf8(Kb + rowK);
            bf16x8 bk1 = ld_bf8(Kb + rowK + 32);
            f32x4 s4 = {};
            s4 = __builtin_amdgcn_mfma_f32_16x16x32_bf16(aq0, bk0, s4, 0, 0, 0);
            s4 = __builtin_amdgcn_mfma_f32_16x16x32_bf16(aq1, bk1, s4, 0, 0, 0);
            int col = kt * 16 + lr;
            #pragma unroll
            for (int i = 0; i < 4; ++i) {
                int q = q0 + lk * 4 + i;
                float s = s4[i] * 0.125f;
                if (mask[maskBase + (size_t)q * SEQ + col]) s = -1e9f;
                float p = ex2((s - m[i]) * LOG2E) * invl[i];
                attn_out[attnBase + (size_t)q * SEQ + col] = p;
                P[w][lk * 4 + i][sub * 16 + lr] = f2bf(p);
            }
        }
        bf16x8 pa = ld_bf8(&P[w][lr][lk * 8]);
        #pragma unroll
        for (int ni = 0; ni < 4; ++ni) {
            bf16x8 bv = ld_bf8(Vt + vtBase + (size_t)(ni * 16 + lr) * SEQ + kt2 * 32 + lk * 8);
            cacc[ni] = __builtin_amdgcn_mfma_f32_16x16x32_bf16(pa, bv, cacc[ni], 0, 0, 0);
        }
    }
    #pragma unroll
    for (int ni = 0; ni < 4; ++ni)
        #pragma unroll
        for (int i = 0; i < 4; ++i) {
            int q = q0 + lk * 4 + i;
            ctx[(size_t)(b * SEQ + q) * DM + h * 64 + ni * 16 + lr] = f2bf(cacc[ni][i]);
        }
}

// ---------------- in-place LayerNorm over d_out[0 : 8192*1024]
__global__ __launch_bounds__(256) void ln_kernel(
    float* __restrict__ io, const float* __restrict__ gamma, const float* __restrict__ beta)
{
    const int t = threadIdx.x;
    const size_t row = blockIdx.x;
    float4 x = *reinterpret_cast<const float4*>(io + row * DM + t * 4);
    float s = x.x + x.y + x.z + x.w;
    float ss = x.x * x.x + x.y * x.y + x.z * x.z + x.w * x.w;
    #pragma unroll
    for (int off = 1; off < 64; off <<= 1) {
        s += __shfl_xor(s, off);
        ss += __shfl_xor(ss, off);
    }
    __shared__ float rs_[4], rss[4];
    __shared__ float s_mu, s_rs;
    const int w = t >> 6, l = t & 63;
    if (l == 0) { rs_[w] = s; rss[w] = ss; }
    __syncthreads();
    if (t == 0) {
        float S = rs_[0] + rs_[1] + rs_[2] + rs_[3];
        float SS = rss[0] + rss[1] + rss[2] + rss[3];
        float mu = S / DM;
        float var = fmaxf(SS / DM - mu * mu, 0.f);
        s_mu = mu;
        s_rs = rsqrtf(var + 1e-5f);
    }
    __syncthreads();
    float mu = s_mu, r = s_rs;
    float4 g = *reinterpret_cast<const float4*>(gamma + t * 4);
    float4 bb = *reinterpret_cast<const float4*>(beta + t * 4);
    float4 y;
    y.x = (x.x - mu) * r * g.x + bb.x;
    y.y = (x.y - mu) * r * g.y + bb.y;
    y.z = (x.z - mu) * r * g.z + bb.z;
    y.w = (x.w - mu) * r * g.w + bb.w;
    *reinterpret_cast<float4*>(io + row * DM + t * 4) = y;
}

extern "C" void kernel_launch(void* const* d_in, const int* in_sizes, int n_in,
                              void* d_out, int out_size, void* d_ws, size_t ws_size,
                              hipStream_t stream) {
    const float* inQ = (const float*)d_in[0];
    const float* inK = (const float*)d_in[1];
    const float* inV = (const float*)d_in[2];
    const unsigned char* mask = (const unsigned char*)d_in[3];
    const float* WQ = (const float*)d_in[4];
    const float* WK = (const float*)d_in[5];
    const float* WV = (const float*)d_in[6];
    const float* Wfc = (const float*)d_in[7];
    const float* gamma = (const float*)d_in[8];
    const float* beta = (const float*)d_in[9];
    float* out = (float*)d_out;

    // workspace layout (needs 80 MiB)
    char* ws = (char*)d_ws;
    const size_t SZ = (size_t)8192 * 1024 * sizeof(u16); // 16 MiB
    u16* Qb = (u16*)(ws);
    u16* Kb = (u16*)(ws + SZ);
    u16* Vb = (u16*)(ws + 2 * SZ);
    u16* Vt = (u16*)(ws + 3 * SZ);
    u16* ctx = (u16*)(ws + 4 * SZ);

    dim3 blk(256);
    proj_gemm<<<dim3(64, 8, 3), blk, 0, stream>>>(inQ, inK, inV, WQ, WK, WV, Qb, Kb, Vb);
    v_transpose<<<dim3(32, 16, 4), blk, 0, stream>>>(Vb, Vt);
    attn_kernel<<<dim3(32, 16, 4), blk, 0, stream>>>(Qb, Kb, Vt, mask, out + 8388608, ctx);
    out_gemm<<<dim3(64, 8), blk, 0, stream>>>(ctx, Wfc, inQ, out);
    ln_kernel<<<8192, blk, 0, stream>>>(out, gamma, beta);
}

// Round 2
// 937.347 us; speedup vs baseline: 1.2981x; 1.2981x over previous
//
#include <hip/hip_runtime.h>
#include <hip/hip_bf16.h>
#include <cstdint>

#define DM   1024
#define SEQ  2048
#define NB   4
#define NH   16
// 0.125 * log2(e): folded into Q projection output so exp2(mfma result) is softmax numerator
#define QSCALE 0.18033688011112042f

typedef __bf16 bf16x8 __attribute__((ext_vector_type(8)));
typedef float  f32x4  __attribute__((ext_vector_type(4)));
typedef unsigned short u16;
typedef u16 u16x4 __attribute__((ext_vector_type(4)));
typedef u16 u16x8 __attribute__((ext_vector_type(8)));

__device__ __forceinline__ u16 f2bf(float f) {
    uint32_t u = __builtin_bit_cast(uint32_t, f);
    u = (u + 0x7FFFu + ((u >> 16) & 1u)) >> 16;
    return (u16)u;
}
__device__ __forceinline__ float ex2(float x) { return __builtin_amdgcn_exp2f(x); }
__device__ __forceinline__ bf16x8 ld_bf8(const u16* p) {
    return __builtin_bit_cast(bf16x8, *reinterpret_cast<const u16x8*>(p));
}

// ---------------- projection GEMM: fp32 A [8192,1024] x fp32 W [1024,1024] -> bf16 out
__global__ __launch_bounds__(256) void proj_gemm(
    const float* __restrict__ A0, const float* __restrict__ A1, const float* __restrict__ A2,
    const float* __restrict__ W0, const float* __restrict__ W1, const float* __restrict__ W2,
    u16* __restrict__ O0, u16* __restrict__ O1, u16* __restrict__ O2)
{
    const float* A; const float* W; u16* Out;
    if (blockIdx.z == 0) { A = A0; W = W0; Out = O0; }
    else if (blockIdx.z == 1) { A = A1; W = W1; Out = O1; }
    else { A = A2; W = W2; Out = O2; }
    const float oscale = (blockIdx.z == 0) ? QSCALE : 1.0f;

    __shared__ u16 As[128][40];
    __shared__ u16 Bs[128][40];
    const int t = threadIdx.x;
    const int m0 = blockIdx.x * 128;
    const int n0 = blockIdx.y * 128;
    const int w = t >> 6, l = t & 63;
    const int wr = (w >> 1) * 64, wc = (w & 1) * 64;
    const int lr = l & 15, lk = l >> 4;

    f32x4 acc[4][4] = {};
    for (int kt = 0; kt < DM; kt += 32) {
        #pragma unroll
        for (int ii = 0; ii < 4; ++ii) {
            int fidx = t + ii * 256;
            int row = fidx >> 3, c4 = fidx & 7;
            const float4 v = *reinterpret_cast<const float4*>(A + (size_t)(m0 + row) * DM + kt + c4 * 4);
            u16x4 o; o[0] = f2bf(v.x); o[1] = f2bf(v.y); o[2] = f2bf(v.z); o[3] = f2bf(v.w);
            *reinterpret_cast<u16x4*>(&As[row][c4 * 4]) = o;
        }
        #pragma unroll
        for (int ii = 0; ii < 4; ++ii) {
            int fidx = t + ii * 256;
            int kk = fidx >> 5, c4 = fidx & 31;
            const float4 v = *reinterpret_cast<const float4*>(W + (size_t)(kt + kk) * DM + n0 + c4 * 4);
            Bs[c4 * 4 + 0][kk] = f2bf(v.x);
            Bs[c4 * 4 + 1][kk] = f2bf(v.y);
            Bs[c4 * 4 + 2][kk] = f2bf(v.z);
            Bs[c4 * 4 + 3][kk] = f2bf(v.w);
        }
        __syncthreads();
        bf16x8 af[4], bfr[4];
        #pragma unroll
        for (int mi = 0; mi < 4; ++mi) af[mi] = ld_bf8(&As[wr + mi * 16 + lr][lk * 8]);
        #pragma unroll
        for (int ni = 0; ni < 4; ++ni) bfr[ni] = ld_bf8(&Bs[wc + ni * 16 + lr][lk * 8]);
        #pragma unroll
        for (int mi = 0; mi < 4; ++mi)
            #pragma unroll
            for (int ni = 0; ni < 4; ++ni)
                acc[mi][ni] = __builtin_amdgcn_mfma_f32_16x16x32_bf16(af[mi], bfr[ni], acc[mi][ni], 0, 0, 0);
        __syncthreads();
    }
    #pragma unroll
    for (int mi = 0; mi < 4; ++mi)
        #pragma unroll
        for (int ni = 0; ni < 4; ++ni)
            #pragma unroll
            for (int i = 0; i < 4; ++i) {
                int r = m0 + wr + mi * 16 + lk * 4 + i;
                int c = n0 + wc + ni * 16 + lr;
                Out[(size_t)r * DM + c] = f2bf(acc[mi][ni][i] * oscale);
            }
}

// ---------------- output GEMM: bf16 ctx [8192,1024] x fp32 W_fc -> fp32 out + residual
__global__ __launch_bounds__(256) void out_gemm(
    const u16* __restrict__ A, const float* __restrict__ W,
    const float* __restrict__ resid, float* __restrict__ Out)
{
    __shared__ u16 As[128][40];
    __shared__ u16 Bs[128][40];
    const int t = threadIdx.x;
    const int m0 = blockIdx.x * 128;
    const int n0 = blockIdx.y * 128;
    const int w = t >> 6, l = t & 63;
    const int wr = (w >> 1) * 64, wc = (w & 1) * 64;
    const int lr = l & 15, lk = l >> 4;

    f32x4 acc[4][4] = {};
    for (int kt = 0; kt < DM; kt += 32) {
        #pragma unroll
        for (int ii = 0; ii < 2; ++ii) {
            int fidx = t + ii * 256;
            int row = fidx >> 2, c8 = fidx & 3;
            u16x8 v = *reinterpret_cast<const u16x8*>(A + (size_t)(m0 + row) * DM + kt + c8 * 8);
            *reinterpret_cast<u16x8*>(&As[row][c8 * 8]) = v;
        }
        #pragma unroll
        for (int ii = 0; ii < 4; ++ii) {
            int fidx = t + ii * 256;
            int kk = fidx >> 5, c4 = fidx & 31;
            const float4 v = *reinterpret_cast<const float4*>(W + (size_t)(kt + kk) * DM + n0 + c4 * 4);
            Bs[c4 * 4 + 0][kk] = f2bf(v.x);
            Bs[c4 * 4 + 1][kk] = f2bf(v.y);
            Bs[c4 * 4 + 2][kk] = f2bf(v.z);
            Bs[c4 * 4 + 3][kk] = f2bf(v.w);
        }
        __syncthreads();
        bf16x8 af[4], bfr[4];
        #pragma unroll
        for (int mi = 0; mi < 4; ++mi) af[mi] = ld_bf8(&As[wr + mi * 16 + lr][lk * 8]);
        #pragma unroll
        for (int ni = 0; ni < 4; ++ni) bfr[ni] = ld_bf8(&Bs[wc + ni * 16 + lr][lk * 8]);
        #pragma unroll
        for (int mi = 0; mi < 4; ++mi)
            #pragma unroll
            for (int ni = 0; ni < 4; ++ni)
                acc[mi][ni] = __builtin_amdgcn_mfma_f32_16x16x32_bf16(af[mi], bfr[ni], acc[mi][ni], 0, 0, 0);
        __syncthreads();
    }
    #pragma unroll
    for (int mi = 0; mi < 4; ++mi)
        #pragma unroll
        for (int ni = 0; ni < 4; ++ni)
            #pragma unroll
            for (int i = 0; i < 4; ++i) {
                int r = m0 + wr + mi * 16 + lk * 4 + i;
                int c = n0 + wc + ni * 16 + lr;
                Out[(size_t)r * DM + c] = acc[mi][ni][i] + resid[(size_t)r * DM + c];
            }
}

// ---------------- V transpose: Vb[b*2048+s][h*64+dv] -> Vt[((b*16+h)*64+dv)][s]
__global__ __launch_bounds__(256) void v_transpose(const u16* __restrict__ Vb, u16* __restrict__ Vt)
{
    __shared__ u16 T[64][72];
    const int t = threadIdx.x;
    const int s0 = blockIdx.x * 64;
    const int h = blockIdx.y, b = blockIdx.z;
    #pragma unroll
    for (int ii = 0; ii < 4; ++ii) {
        int fidx = t + ii * 256;
        int row = fidx >> 4, c4 = fidx & 15;
        u16x4 v = *reinterpret_cast<const u16x4*>(Vb + (size_t)(b * SEQ + s0 + row) * DM + h * 64 + c4 * 4);
        T[c4 * 4 + 0][row] = v[0];
        T[c4 * 4 + 1][row] = v[1];
        T[c4 * 4 + 2][row] = v[2];
        T[c4 * 4 + 3][row] = v[3];
    }
    __syncthreads();
    #pragma unroll
    for (int ii = 0; ii < 4; ++ii) {
        int fidx = t + ii * 256;
        int dv = fidx >> 4, s4 = fidx & 15;
        u16x4 v;
        v[0] = T[dv][s4 * 4 + 0]; v[1] = T[dv][s4 * 4 + 1];
        v[2] = T[dv][s4 * 4 + 2]; v[3] = T[dv][s4 * 4 + 3];
        *reinterpret_cast<u16x4*>(Vt + ((size_t)((b * NH + h) * 64 + dv)) * SEQ + s0 + s4 * 4) = v;
    }
}

// ---------------- mask bit-pack: mask bytes (0/1) -> 1 bit per col.
// mbits[b][q][w32]: u32 word w covers cols w*32..w*32+31. 4*2048*64 words = 2 MiB.
__global__ __launch_bounds__(256) void mask_pack(const unsigned char* __restrict__ mask,
                                                 uint32_t* __restrict__ mbits)
{
    size_t idx = (size_t)blockIdx.x * 256 + threadIdx.x;   // one u32 word per thread
    const uint32_t* m32 = reinterpret_cast<const uint32_t*>(mask + idx * 32);
    uint32_t out = 0;
    #pragma unroll
    for (int j = 0; j < 8; ++j) {
        uint32_t y = m32[j] & 0x01010101u;
        uint32_t nib = (y * 0x01020408u) >> 24;   // gathers the 4 byte-LSBs into bits 0..3
        out |= nib << (j * 4);
    }
    mbits[idx] = out;
}

// ---------------- attention v2: no-max softmax (scores bounded), bitmask, K in LDS
// block = (qt, h, b): 64 q rows, 4 waves x 16 rows. Two passes over 16 chunks of 128 K-rows.
#define NEGINF __builtin_bit_cast(float, 0xFF800000u)
__global__ __launch_bounds__(256) void attn_kernel(
    const u16* __restrict__ Qb, const u16* __restrict__ Kb, const u16* __restrict__ Vt,
    const unsigned char* __restrict__ mbytes,   // bit-packed mask, 256 B per (b,q) row
    float* __restrict__ attn_out, u16* __restrict__ ctx)
{
    __shared__ u16 Kbuf[2][8192];        // 2 x (128 rows x 64 d) bf16, XOR-swizzled, 32 KiB
    __shared__ u16 P[4][16][40];
    const int t = threadIdx.x;
    const int w = t >> 6, l = t & 63;
    const int lr = l & 15, lk = l >> 4;
    const int qt = blockIdx.x, h = blockIdx.y, b = blockIdx.z;
    const int q0 = qt * 64 + w * 16;

    // Q fragments (already scaled by 0.125*log2e at projection)
    const size_t rowQ = (size_t)(b * SEQ + q0 + lr) * DM + h * 64 + lk * 8;
    const bf16x8 aq0 = ld_bf8(Qb + rowQ);
    const bf16x8 aq1 = ld_bf8(Qb + rowQ + 32);

    // staging geometry: lane writes LDS bytes [inst*4096 + w*1024 + l*16)
    const int st_row0 = w * 8 + (l >> 3);                     // chunk-local K row, inst 0
    const int st_col  = (((l & 7) ^ (l >> 3)) << 4) >> 1;     // pre-swizzled col (u16 units)
    const u16* kgbase = Kb + (size_t)(b * SEQ) * DM + h * 64;

    #define STAGE(c, buf)                                                              \
        {   _Pragma("unroll")                                                          \
            for (int inst = 0; inst < 4; ++inst) {                                     \
                const u16* src = kgbase + (size_t)((c) * 128 + st_row0 + inst * 32) * DM + st_col; \
                u16* dst = &Kbuf[buf][inst * 2048 + w * 512];                          \
                __builtin_amdgcn_global_load_lds(src, dst, 16, 0, 0);                  \
            }                                                                          \
        }

    // mask row base pointers (256 B per q row)
    const unsigned char* mrow[4];
    #pragma unroll
    for (int i = 0; i < 4; ++i)
        mrow[i] = mbytes + (((size_t)(b * SEQ) + q0 + lk * 4 + i) << 8);

    // QK^T tile from swizzled LDS chunk: rows tile16..tile16+15, all 64 d
    const int swz = (lr & 7) << 4;
    #define QK_TILE(kb, tile16, s4out)                                                  \
        {   const char* base_ = (const char*)(kb) + ((tile16) + lr) * 128;              \
            bf16x8 bk0_ = ld_bf8((const u16*)(base_ + ((lk * 16) ^ swz)));              \
            bf16x8 bk1_ = ld_bf8((const u16*)(base_ + ((64 + lk * 16) ^ swz)));         \
            s4out = __builtin_amdgcn_mfma_f32_16x16x32_bf16(aq0, bk0_, (f32x4){}, 0, 0, 0); \
            s4out = __builtin_amdgcn_mfma_f32_16x16x32_bf16(aq1, bk1_, s4out, 0, 0, 0); \
        }

    // -------- pass 1: row sums of exp2(scores)
    float sum[4] = {0.f, 0.f, 0.f, 0.f};
    STAGE(0, 0);
    __syncthreads();
    for (int c = 0; c < 16; ++c) {
        const int buf = c & 1;
        if (c + 1 < 16) STAGE(c + 1, buf ^ 1);
        const u16* kb = &Kbuf[buf][0];
        #pragma unroll
        for (int g = 0; g < 2; ++g) {
            unsigned long long mws[4];
            #pragma unroll
            for (int i = 0; i < 4; ++i)
                mws[i] = (*reinterpret_cast<const unsigned long long*>(mrow[i] + c * 16 + g * 8)) >> lr;
            #pragma unroll
            for (int tt = 0; tt < 4; ++tt) {
                f32x4 s4;
                QK_TILE(kb, (g * 4 + tt) * 16, s4);
                #pragma unroll
                for (int i = 0; i < 4; ++i) {
                    float sv = s4[i];
                    if ((mws[i] >> (tt * 16)) & 1ull) sv = NEGINF;
                    sum[i] += ex2(sv);
                }
            }
        }
        __syncthreads();
    }
    // reduce across the 16 lanes (lr) holding each row
    #pragma unroll
    for (int i = 0; i < 4; ++i) {
        #pragma unroll
        for (int off = 1; off < 16; off <<= 1) sum[i] += __shfl_xor(sum[i], off);
    }
    float invl[4];
    #pragma unroll
    for (int i = 0; i < 4; ++i) invl[i] = 1.0f / sum[i];

    // -------- pass 2: normalized attn writes + PV accumulate
    f32x4 cacc[4] = {};
    const size_t attnBase = (size_t)(b * NH + h) * SEQ * SEQ;
    const size_t vtBase = (size_t)((b * NH + h) * 64) * SEQ;
    STAGE(0, 0);
    __syncthreads();
    for (int c = 0; c < 16; ++c) {
        const int buf = c & 1;
        if (c + 1 < 16) STAGE(c + 1, buf ^ 1);
        const u16* kb = &Kbuf[buf][0];
        #pragma unroll
        for (int g = 0; g < 2; ++g) {
            unsigned long long mws[4];
            #pragma unroll
            for (int i = 0; i < 4; ++i)
                mws[i] = (*reinterpret_cast<const unsigned long long*>(mrow[i] + c * 16 + g * 8)) >> lr;
            #pragma unroll
            for (int hs = 0; hs < 2; ++hs) {
                #pragma unroll
                for (int tt2 = 0; tt2 < 2; ++tt2) {
                    const int tl = hs * 2 + tt2;              // tile within 64-col group
                    f32x4 s4;
                    QK_TILE(kb, (g * 4 + tl) * 16, s4);
                    const int col = c * 128 + g * 64 + tl * 16 + lr;
                    #pragma unroll
                    for (int i = 0; i < 4; ++i) {
                        float sv = s4[i];
                        if ((mws[i] >> (tl * 16)) & 1ull) sv = NEGINF;
                        float p = ex2(sv);
                        int q = q0 + lk * 4 + i;
                        attn_out[attnBase + (size_t)q * SEQ + col] = p * invl[i];
                        uint32_t ub = __builtin_bit_cast(uint32_t, p);
                        P[w][lk * 4 + i][tt2 * 16 + lr] = (u16)((ub + 0x8000u) >> 16);
                    }
                }
                // PV over these 32 cols (unnormalized; scaled at the end)
                bf16x8 pa = ld_bf8(&P[w][lr][lk * 8]);
                const int cc = c * 128 + g * 64 + hs * 32;
                #pragma unroll
                for (int ni = 0; ni < 4; ++ni) {
                    bf16x8 bv = ld_bf8(Vt + vtBase + (size_t)(ni * 16 + lr) * SEQ + cc + lk * 8);
                    cacc[ni] = __builtin_amdgcn_mfma_f32_16x16x32_bf16(pa, bv, cacc[ni], 0, 0, 0);
                }
            }
        }
        __syncthreads();
    }
    #pragma unroll
    for (int ni = 0; ni < 4; ++ni)
        #pragma unroll
        for (int i = 0; i < 4; ++i) {
            int q = q0 + lk * 4 + i;
            ctx[(size_t)(b * SEQ + q) * DM + h * 64 + ni * 16 + lr] = f2bf(cacc[ni][i] * invl[i]);
        }
    #undef STAGE
    #undef QK_TILE
}

// ---------------- in-place LayerNorm over d_out[0 : 8192*1024]
__global__ __launch_bounds__(256) void ln_kernel(
    float* __restrict__ io, const float* __restrict__ gamma, const float* __restrict__ beta)
{
    const int t = threadIdx.x;
    const size_t row = blockIdx.x;
    float4 x = *reinterpret_cast<const float4*>(io + row * DM + t * 4);
    float s = x.x + x.y + x.z + x.w;
    float ss = x.x * x.x + x.y * x.y + x.z * x.z + x.w * x.w;
    #pragma unroll
    for (int off = 1; off < 64; off <<= 1) {
        s += __shfl_xor(s, off);
        ss += __shfl_xor(ss, off);
    }
    __shared__ float rs_[4], rss[4];
    __shared__ float s_mu, s_rs;
    const int w = t >> 6, l = t & 63;
    if (l == 0) { rs_[w] = s; rss[w] = ss; }
    __syncthreads();
    if (t == 0) {
        float S = rs_[0] + rs_[1] + rs_[2] + rs_[3];
        float SS = rss[0] + rss[1] + rss[2] + rss[3];
        float mu = S / DM;
        float var = fmaxf(SS / DM - mu * mu, 0.f);
        s_mu = mu;
        s_rs = rsqrtf(var + 1e-5f);
    }
    __syncthreads();
    float mu = s_mu, r = s_rs;
    float4 g = *reinterpret_cast<const float4*>(gamma + t * 4);
    float4 bb = *reinterpret_cast<const float4*>(beta + t * 4);
    float4 y;
    y.x = (x.x - mu) * r * g.x + bb.x;
    y.y = (x.y - mu) * r * g.y + bb.y;
    y.z = (x.z - mu) * r * g.z + bb.z;
    y.w = (x.w - mu) * r * g.w + bb.w;
    *reinterpret_cast<float4*>(io + row * DM + t * 4) = y;
}

extern "C" void kernel_launch(void* const* d_in, const int* in_sizes, int n_in,
                              void* d_out, int out_size, void* d_ws, size_t ws_size,
                              hipStream_t stream) {
    const float* inQ = (const float*)d_in[0];
    const float* inK = (const float*)d_in[1];
    const float* inV = (const float*)d_in[2];
    const unsigned char* mask = (const unsigned char*)d_in[3];
    const float* WQ = (const float*)d_in[4];
    const float* WK = (const float*)d_in[5];
    const float* WV = (const float*)d_in[6];
    const float* Wfc = (const float*)d_in[7];
    const float* gamma = (const float*)d_in[8];
    const float* beta = (const float*)d_in[9];
    float* out = (float*)d_out;

    // workspace layout (80 MiB)
    char* ws = (char*)d_ws;
    const size_t SZ = (size_t)8192 * 1024 * sizeof(u16); // 16 MiB
    u16* Qb = (u16*)(ws);
    u16* Kb = (u16*)(ws + SZ);
    u16* Vb = (u16*)(ws + 2 * SZ);
    u16* Vt = (u16*)(ws + 3 * SZ);
    u16* ctx = (u16*)(ws + 4 * SZ);
    // mbits reuses Vb's region (Vb is dead after v_transpose; mask_pack runs after it)
    uint32_t* mbits = (uint32_t*)(ws + 2 * SZ);

    dim3 blk(256);
    proj_gemm<<<dim3(64, 8, 3), blk, 0, stream>>>(inQ, inK, inV, WQ, WK, WV, Qb, Kb, Vb);
    v_transpose<<<dim3(32, 16, 4), blk, 0, stream>>>(Vb, Vt);
    mask_pack<<<dim3(2048), blk, 0, stream>>>(mask, mbits);
    attn_kernel<<<dim3(32, 16, 4), blk, 0, stream>>>(Qb, Kb, Vt, (const unsigned char*)mbits,
                                                     out + 8388608, ctx);
    out_gemm<<<dim3(64, 8), blk, 0, stream>>>(ctx, Wfc, inQ, out);
    ln_kernel<<<8192, blk, 0, stream>>>(out, gamma, beta);
}

// Round 3
// 744.815 us; speedup vs baseline: 1.6337x; 1.2585x over previous
//
#include <hip/hip_runtime.h>
#include <hip/hip_bf16.h>
#include <cstdint>

#define DM   1024
#define SEQ  2048
#define NB   4
#define NH   16
// 0.125 * log2(e): folded into W_Q at conversion so exp2(mfma result) is the softmax numerator
#define QSCALE 0.18033688011112042f
#define NEGINF __builtin_bit_cast(float, 0xFF800000u)

typedef __bf16 bf16x8 __attribute__((ext_vector_type(8)));
typedef float  f32x4  __attribute__((ext_vector_type(4)));
typedef unsigned short u16;
typedef u16 u16x4 __attribute__((ext_vector_type(4)));
typedef u16 u16x8 __attribute__((ext_vector_type(8)));

__device__ __forceinline__ u16 f2bf(float f) {
    uint32_t u = __builtin_bit_cast(uint32_t, f);
    u = (u + 0x7FFFu + ((u >> 16) & 1u)) >> 16;
    return (u16)u;
}
__device__ __forceinline__ float ex2(float x) { return __builtin_amdgcn_exp2f(x); }
__device__ __forceinline__ bf16x8 ld_bf8(const u16* p) {
    return __builtin_bit_cast(bf16x8, *reinterpret_cast<const u16x8*>(p));
}

// ---------------- weight convert + transpose: W fp32 [k][n] -> Wt bf16 [n][k] (scaled)
__global__ __launch_bounds__(256) void conv_wt(
    const float* __restrict__ W0, const float* __restrict__ W1,
    const float* __restrict__ W2, const float* __restrict__ W3,
    u16* __restrict__ T0, u16* __restrict__ T1, u16* __restrict__ T2, u16* __restrict__ T3)
{
    const float* W; u16* O; float sc = 1.0f;
    if (blockIdx.z == 0)      { W = W0; O = T0; sc = QSCALE; }
    else if (blockIdx.z == 1) { W = W1; O = T1; }
    else if (blockIdx.z == 2) { W = W2; O = T2; }
    else                      { W = W3; O = T3; }
    __shared__ u16 T[64][72];
    const int t = threadIdx.x;
    const int k0 = blockIdx.x * 64, n0 = blockIdx.y * 64;
    #pragma unroll
    for (int ii = 0; ii < 4; ++ii) {
        int fidx = t + ii * 256;
        int row = fidx >> 4, c4 = fidx & 15;       // row = k-local, c4*4.. = n-local
        float4 v = *reinterpret_cast<const float4*>(W + (size_t)(k0 + row) * DM + n0 + c4 * 4);
        T[c4 * 4 + 0][row] = f2bf(v.x * sc);
        T[c4 * 4 + 1][row] = f2bf(v.y * sc);
        T[c4 * 4 + 2][row] = f2bf(v.z * sc);
        T[c4 * 4 + 3][row] = f2bf(v.w * sc);
    }
    __syncthreads();
    #pragma unroll
    for (int ii = 0; ii < 4; ++ii) {
        int fidx = t + ii * 256;
        int row = fidx >> 4, c4 = fidx & 15;       // row = n-local, c4*4.. = k-local
        u16x4 v;
        v[0] = T[row][c4 * 4 + 0]; v[1] = T[row][c4 * 4 + 1];
        v[2] = T[row][c4 * 4 + 2]; v[3] = T[row][c4 * 4 + 3];
        *reinterpret_cast<u16x4*>(O + (size_t)(n0 + row) * DM + k0 + c4 * 4) = v;
    }
}

// ---------------- projection GEMM: fp32 A [8192,1024] x bf16 Wt [n][k] -> bf16 out
__global__ __launch_bounds__(256) void proj_gemm(
    const float* __restrict__ A0, const float* __restrict__ A1, const float* __restrict__ A2,
    const u16* __restrict__ B0, const u16* __restrict__ B1, const u16* __restrict__ B2,
    u16* __restrict__ O0, u16* __restrict__ O1, u16* __restrict__ O2)
{
    const float* A; const u16* Bw; u16* Out;
    if (blockIdx.z == 0)      { A = A0; Bw = B0; Out = O0; }
    else if (blockIdx.z == 1) { A = A1; Bw = B1; Out = O1; }
    else                      { A = A2; Bw = B2; Out = O2; }

    __shared__ u16 As[128][40];     // padded; fp32->bf16 converted via VALU
    __shared__ u16 Bs[128 * 32];    // linear; staged via global_load_lds (conflict-free: 64B rows)
    const int t = threadIdx.x;
    const int m0 = blockIdx.x * 128;
    const int n0 = blockIdx.y * 128;
    const int w = t >> 6, l = t & 63;
    const int wr = (w >> 1) * 64, wc = (w & 1) * 64;
    const int lr = l & 15, lk = l >> 4;
    const int brow = w * 16 + (l >> 2);            // B-stage row within 64-row group
    const int bcol = (l & 3) * 8;                  // B-stage k offset (u16)

    f32x4 acc[4][4] = {};
    for (int kt = 0; kt < DM; kt += 32) {
        #pragma unroll
        for (int inst = 0; inst < 2; ++inst) {
            const u16* src = Bw + (size_t)(n0 + inst * 64 + brow) * DM + kt + bcol;
            __builtin_amdgcn_global_load_lds(src, &Bs[inst * 2048 + w * 512], 16, 0, 0);
        }
        #pragma unroll
        for (int ii = 0; ii < 4; ++ii) {
            int fidx = t + ii * 256;
            int row = fidx >> 3, c4 = fidx & 7;
            const float4 v = *reinterpret_cast<const float4*>(A + (size_t)(m0 + row) * DM + kt + c4 * 4);
            u16x4 o; o[0] = f2bf(v.x); o[1] = f2bf(v.y); o[2] = f2bf(v.z); o[3] = f2bf(v.w);
            *reinterpret_cast<u16x4*>(&As[row][c4 * 4]) = o;
        }
        __syncthreads();
        bf16x8 af[4], bfr[4];
        #pragma unroll
        for (int mi = 0; mi < 4; ++mi) af[mi] = ld_bf8(&As[wr + mi * 16 + lr][lk * 8]);
        #pragma unroll
        for (int ni = 0; ni < 4; ++ni) bfr[ni] = ld_bf8(&Bs[(wc + ni * 16 + lr) * 32 + lk * 8]);
        #pragma unroll
        for (int mi = 0; mi < 4; ++mi)
            #pragma unroll
            for (int ni = 0; ni < 4; ++ni)
                acc[mi][ni] = __builtin_amdgcn_mfma_f32_16x16x32_bf16(af[mi], bfr[ni], acc[mi][ni], 0, 0, 0);
        __syncthreads();
    }
    #pragma unroll
    for (int mi = 0; mi < 4; ++mi)
        #pragma unroll
        for (int ni = 0; ni < 4; ++ni)
            #pragma unroll
            for (int i = 0; i < 4; ++i) {
                int r = m0 + wr + mi * 16 + lk * 4 + i;
                int c = n0 + wc + ni * 16 + lr;
                Out[(size_t)r * DM + c] = f2bf(acc[mi][ni][i]);
            }
}

// ---------------- output GEMM: bf16 ctx x bf16 WtF [n][k] -> fp32 out + residual
__global__ __launch_bounds__(256) void out_gemm(
    const u16* __restrict__ A, const u16* __restrict__ Bw,
    const float* __restrict__ resid, float* __restrict__ Out)
{
    __shared__ u16 As[128 * 32];
    __shared__ u16 Bs[128 * 32];
    const int t = threadIdx.x;
    const int m0 = blockIdx.x * 128;
    const int n0 = blockIdx.y * 128;
    const int w = t >> 6, l = t & 63;
    const int wr = (w >> 1) * 64, wc = (w & 1) * 64;
    const int lr = l & 15, lk = l >> 4;
    const int srow = w * 16 + (l >> 2);
    const int scol = (l & 3) * 8;

    f32x4 acc[4][4] = {};
    for (int kt = 0; kt < DM; kt += 32) {
        #pragma unroll
        for (int inst = 0; inst < 2; ++inst) {
            const u16* srcA = A  + (size_t)(m0 + inst * 64 + srow) * DM + kt + scol;
            const u16* srcB = Bw + (size_t)(n0 + inst * 64 + srow) * DM + kt + scol;
            __builtin_amdgcn_global_load_lds(srcA, &As[inst * 2048 + w * 512], 16, 0, 0);
            __builtin_amdgcn_global_load_lds(srcB, &Bs[inst * 2048 + w * 512], 16, 0, 0);
        }
        __syncthreads();
        bf16x8 af[4], bfr[4];
        #pragma unroll
        for (int mi = 0; mi < 4; ++mi) af[mi] = ld_bf8(&As[(wr + mi * 16 + lr) * 32 + lk * 8]);
        #pragma unroll
        for (int ni = 0; ni < 4; ++ni) bfr[ni] = ld_bf8(&Bs[(wc + ni * 16 + lr) * 32 + lk * 8]);
        #pragma unroll
        for (int mi = 0; mi < 4; ++mi)
            #pragma unroll
            for (int ni = 0; ni < 4; ++ni)
                acc[mi][ni] = __builtin_amdgcn_mfma_f32_16x16x32_bf16(af[mi], bfr[ni], acc[mi][ni], 0, 0, 0);
        __syncthreads();
    }
    #pragma unroll
    for (int mi = 0; mi < 4; ++mi)
        #pragma unroll
        for (int ni = 0; ni < 4; ++ni)
            #pragma unroll
            for (int i = 0; i < 4; ++i) {
                int r = m0 + wr + mi * 16 + lk * 4 + i;
                int c = n0 + wc + ni * 16 + lr;
                Out[(size_t)r * DM + c] = acc[mi][ni][i] + resid[(size_t)r * DM + c];
            }
}

// ---------------- V transpose: Vp[b*2048+s][h*64+dv] -> Vt[((b*16+h)*64+dv)][s]
__global__ __launch_bounds__(256) void v_transpose(const u16* __restrict__ Vp, u16* __restrict__ Vt)
{
    __shared__ u16 T[64][72];
    const int t = threadIdx.x;
    const int s0 = blockIdx.x * 64;
    const int h = blockIdx.y, b = blockIdx.z;
    #pragma unroll
    for (int ii = 0; ii < 4; ++ii) {
        int fidx = t + ii * 256;
        int row = fidx >> 4, c4 = fidx & 15;
        u16x4 v = *reinterpret_cast<const u16x4*>(Vp + (size_t)(b * SEQ + s0 + row) * DM + h * 64 + c4 * 4);
        T[c4 * 4 + 0][row] = v[0];
        T[c4 * 4 + 1][row] = v[1];
        T[c4 * 4 + 2][row] = v[2];
        T[c4 * 4 + 3][row] = v[3];
    }
    __syncthreads();
    #pragma unroll
    for (int ii = 0; ii < 4; ++ii) {
        int fidx = t + ii * 256;
        int dv = fidx >> 4, s4 = fidx & 15;
        u16x4 v;
        v[0] = T[dv][s4 * 4 + 0]; v[1] = T[dv][s4 * 4 + 1];
        v[2] = T[dv][s4 * 4 + 2]; v[3] = T[dv][s4 * 4 + 3];
        *reinterpret_cast<u16x4*>(Vt + ((size_t)((b * NH + h) * 64 + dv)) * SEQ + s0 + s4 * 4) = v;
    }
}

// ---------------- mask bit-pack: mask bytes (0/1) -> 1 bit per col
__global__ __launch_bounds__(256) void mask_pack(const unsigned char* __restrict__ mask,
                                                 uint32_t* __restrict__ mbits)
{
    size_t idx = (size_t)blockIdx.x * 256 + threadIdx.x;
    const uint32_t* m32 = reinterpret_cast<const uint32_t*>(mask + idx * 32);
    uint32_t out = 0;
    #pragma unroll
    for (int j = 0; j < 8; ++j) {
        uint32_t y = m32[j] & 0x01010101u;
        uint32_t nib = (y * 0x01020408u) >> 24;
        out |= nib << (j * 4);
    }
    mbits[idx] = out;
}

// ---------------- attention v3: 64-row K chunks (21.5 KB LDS -> 7 blocks/CU), bitmask,
// no-max softmax, two passes. Block = (qt, h, b): 64 q rows, 4 waves x 16 rows.
__global__ __launch_bounds__(256) void attn_kernel(
    const u16* __restrict__ Qb, const u16* __restrict__ Kb, const u16* __restrict__ Vt,
    const unsigned char* __restrict__ mbytes,
    float* __restrict__ attn_out, u16* __restrict__ ctx)
{
    __shared__ u16 Kbuf[2][4096];        // 2 x (64 rows x 64 d) bf16, XOR-swizzled, 16 KiB
    __shared__ u16 P[4][16][40];
    const int t = threadIdx.x;
    const int w = t >> 6, l = t & 63;
    const int lr = l & 15, lk = l >> 4;
    const int qt = blockIdx.x, h = blockIdx.y, b = blockIdx.z;
    const int q0 = qt * 64 + w * 16;

    const size_t rowQ = (size_t)(b * SEQ + q0 + lr) * DM + h * 64 + lk * 8;
    const bf16x8 aq0 = ld_bf8(Qb + rowQ);
    const bf16x8 aq1 = ld_bf8(Qb + rowQ + 32);

    // staging: per inst 32 rows; lane l -> row w*8+(l>>3), pre-swizzled col block (l&7)^(l>>3)
    const int st_row0 = w * 8 + (l >> 3);
    const int st_col  = ((l & 7) ^ (l >> 3)) * 8;   // u16 units
    const u16* kgbase = Kb + (size_t)(b * SEQ) * DM + h * 64;

    #define STAGE(c, buf)                                                                   \
        {   _Pragma("unroll")                                                               \
            for (int inst = 0; inst < 2; ++inst) {                                          \
                const u16* src = kgbase + (size_t)((c) * 64 + inst * 32 + st_row0) * DM + st_col; \
                __builtin_amdgcn_global_load_lds(src, &Kbuf[buf][inst * 2048 + w * 512], 16, 0, 0); \
            }                                                                               \
        }

    const unsigned char* mrow[4];
    #pragma unroll
    for (int i = 0; i < 4; ++i)
        mrow[i] = mbytes + (((size_t)(b * SEQ) + q0 + lk * 4 + i) << 8);

    const int swz = (lr & 7) << 4;
    #define QK_TILE(kb, tile16, s4out)                                                      \
        {   const char* base_ = (const char*)(kb) + ((tile16) + lr) * 128;                  \
            bf16x8 bk0_ = ld_bf8((const u16*)(base_ + ((lk * 16) ^ swz)));                  \
            bf16x8 bk1_ = ld_bf8((const u16*)(base_ + ((64 + lk * 16) ^ swz)));             \
            s4out = __builtin_amdgcn_mfma_f32_16x16x32_bf16(aq0, bk0_, (f32x4){}, 0, 0, 0); \
            s4out = __builtin_amdgcn_mfma_f32_16x16x32_bf16(aq1, bk1_, s4out, 0, 0, 0);     \
        }

    // -------- pass 1: row sums of exp2(scores)
    float sum[4] = {0.f, 0.f, 0.f, 0.f};
    STAGE(0, 0);
    __syncthreads();
    for (int c = 0; c < 32; ++c) {
        const int buf = c & 1;
        if (c + 1 < 32) STAGE(c + 1, buf ^ 1);
        const u16* kb = &Kbuf[buf][0];
        unsigned long long mws[4];
        #pragma unroll
        for (int i = 0; i < 4; ++i)
            mws[i] = (*reinterpret_cast<const unsigned long long*>(mrow[i] + c * 8)) >> lr;
        #pragma unroll
        for (int tt = 0; tt < 4; ++tt) {
            f32x4 s4;
            QK_TILE(kb, tt * 16, s4);
            #pragma unroll
            for (int i = 0; i < 4; ++i) {
                float sv = s4[i];
                if ((mws[i] >> (tt * 16)) & 1ull) sv = NEGINF;
                sum[i] += ex2(sv);
            }
        }
        __syncthreads();
    }
    #pragma unroll
    for (int i = 0; i < 4; ++i) {
        #pragma unroll
        for (int off = 1; off < 16; off <<= 1) sum[i] += __shfl_xor(sum[i], off);
    }
    float invl[4];
    #pragma unroll
    for (int i = 0; i < 4; ++i) invl[i] = 1.0f / sum[i];

    // -------- pass 2: normalized attn writes + PV accumulate
    f32x4 cacc[4] = {};
    const size_t attnBase = (size_t)(b * NH + h) * SEQ * SEQ;
    const size_t vtBase = (size_t)((b * NH + h) * 64) * SEQ;
    STAGE(0, 0);
    __syncthreads();
    for (int c = 0; c < 32; ++c) {
        const int buf = c & 1;
        if (c + 1 < 32) STAGE(c + 1, buf ^ 1);
        const u16* kb = &Kbuf[buf][0];
        unsigned long long mws[4];
        #pragma unroll
        for (int i = 0; i < 4; ++i)
            mws[i] = (*reinterpret_cast<const unsigned long long*>(mrow[i] + c * 8)) >> lr;
        #pragma unroll
        for (int hs = 0; hs < 2; ++hs) {
            #pragma unroll
            for (int tt2 = 0; tt2 < 2; ++tt2) {
                const int tl = hs * 2 + tt2;
                f32x4 s4;
                QK_TILE(kb, tl * 16, s4);
                const int col = c * 64 + tl * 16 + lr;
                #pragma unroll
                for (int i = 0; i < 4; ++i) {
                    float sv = s4[i];
                    if ((mws[i] >> (tl * 16)) & 1ull) sv = NEGINF;
                    float p = ex2(sv);
                    int q = q0 + lk * 4 + i;
                    attn_out[attnBase + (size_t)q * SEQ + col] = p * invl[i];
                    uint32_t ub = __builtin_bit_cast(uint32_t, p);
                    P[w][lk * 4 + i][tt2 * 16 + lr] = (u16)((ub + 0x8000u) >> 16);
                }
            }
            bf16x8 pa = ld_bf8(&P[w][lr][lk * 8]);
            const int cc = c * 64 + hs * 32;
            __builtin_amdgcn_s_setprio(1);
            #pragma unroll
            for (int ni = 0; ni < 4; ++ni) {
                bf16x8 bv = ld_bf8(Vt + vtBase + (size_t)(ni * 16 + lr) * SEQ + cc + lk * 8);
                cacc[ni] = __builtin_amdgcn_mfma_f32_16x16x32_bf16(pa, bv, cacc[ni], 0, 0, 0);
            }
            __builtin_amdgcn_s_setprio(0);
        }
        __syncthreads();
    }
    #pragma unroll
    for (int ni = 0; ni < 4; ++ni)
        #pragma unroll
        for (int i = 0; i < 4; ++i) {
            int q = q0 + lk * 4 + i;
            ctx[(size_t)(b * SEQ + q) * DM + h * 64 + ni * 16 + lr] = f2bf(cacc[ni][i] * invl[i]);
        }
    #undef STAGE
    #undef QK_TILE
}

// ---------------- in-place LayerNorm over d_out[0 : 8192*1024]
__global__ __launch_bounds__(256) void ln_kernel(
    float* __restrict__ io, const float* __restrict__ gamma, const float* __restrict__ beta)
{
    const int t = threadIdx.x;
    const size_t row = blockIdx.x;
    float4 x = *reinterpret_cast<const float4*>(io + row * DM + t * 4);
    float s = x.x + x.y + x.z + x.w;
    float ss = x.x * x.x + x.y * x.y + x.z * x.z + x.w * x.w;
    #pragma unroll
    for (int off = 1; off < 64; off <<= 1) {
        s += __shfl_xor(s, off);
        ss += __shfl_xor(ss, off);
    }
    __shared__ float rs_[4], rss[4];
    __shared__ float s_mu, s_rs;
    const int w = t >> 6, l = t & 63;
    if (l == 0) { rs_[w] = s; rss[w] = ss; }
    __syncthreads();
    if (t == 0) {
        float S = rs_[0] + rs_[1] + rs_[2] + rs_[3];
        float SS = rss[0] + rss[1] + rss[2] + rss[3];
        float mu = S / DM;
        float var = fmaxf(SS / DM - mu * mu, 0.f);
        s_mu = mu;
        s_rs = rsqrtf(var + 1e-5f);
    }
    __syncthreads();
    float mu = s_mu, r = s_rs;
    float4 g = *reinterpret_cast<const float4*>(gamma + t * 4);
    float4 bb = *reinterpret_cast<const float4*>(beta + t * 4);
    float4 y;
    y.x = (x.x - mu) * r * g.x + bb.x;
    y.y = (x.y - mu) * r * g.y + bb.y;
    y.z = (x.z - mu) * r * g.z + bb.z;
    y.w = (x.w - mu) * r * g.w + bb.w;
    *reinterpret_cast<float4*>(io + row * DM + t * 4) = y;
}

extern "C" void kernel_launch(void* const* d_in, const int* in_sizes, int n_in,
                              void* d_out, int out_size, void* d_ws, size_t ws_size,
                              hipStream_t stream) {
    const float* inQ = (const float*)d_in[0];
    const float* inK = (const float*)d_in[1];
    const float* inV = (const float*)d_in[2];
    const unsigned char* mask = (const unsigned char*)d_in[3];
    const float* WQ = (const float*)d_in[4];
    const float* WK = (const float*)d_in[5];
    const float* WV = (const float*)d_in[6];
    const float* Wfc = (const float*)d_in[7];
    const float* gamma = (const float*)d_in[8];
    const float* beta = (const float*)d_in[9];
    float* out = (float*)d_out;

    // workspace layout (80 MiB total, SZ = 16 MiB):
    //  [0,SZ)    Qb
    //  [SZ,2SZ)  Kb
    //  [2SZ,3SZ) WtQ|WtK|WtV|WtF (4 x 2 MiB) + mbits (2 MiB at +8 MiB)
    //  [3SZ,4SZ) Vt
    //  [4SZ,5SZ) V-projection, later overwritten by ctx (V dead after v_transpose)
    char* ws = (char*)d_ws;
    const size_t SZ = (size_t)8192 * 1024 * sizeof(u16);
    u16* Qb  = (u16*)(ws);
    u16* Kb  = (u16*)(ws + SZ);
    u16* WtQ = (u16*)(ws + 2 * SZ);
    u16* WtK = WtQ + (size_t)1024 * 1024;
    u16* WtV = WtK + (size_t)1024 * 1024;
    u16* WtF = WtV + (size_t)1024 * 1024;
    uint32_t* mbits = (uint32_t*)(ws + 2 * SZ + ((size_t)8 << 20));
    u16* Vt  = (u16*)(ws + 3 * SZ);
    u16* Vp  = (u16*)(ws + 4 * SZ);   // V projection
    u16* ctx = (u16*)(ws + 4 * SZ);   // reused after v_transpose

    dim3 blk(256);
    conv_wt<<<dim3(16, 16, 4), blk, 0, stream>>>(WQ, WK, WV, Wfc, WtQ, WtK, WtV, WtF);
    mask_pack<<<dim3(2048), blk, 0, stream>>>(mask, mbits);
    proj_gemm<<<dim3(64, 8, 3), blk, 0, stream>>>(inQ, inK, inV, WtQ, WtK, WtV, Qb, Kb, Vp);
    v_transpose<<<dim3(32, 16, 4), blk, 0, stream>>>(Vp, Vt);
    attn_kernel<<<dim3(32, 16, 4), blk, 0, stream>>>(Qb, Kb, Vt, (const unsigned char*)mbits,
                                                     out + 8388608, ctx);
    out_gemm<<<dim3(64, 8), blk, 0, stream>>>(ctx, WtF, inQ, out);
    ln_kernel<<<8192, blk, 0, stream>>>(out, gamma, beta);
}